// Round 6
// baseline (410.424 us; speedup 1.0000x reference)
//
#include <hip/hip_runtime.h>
#include <math.h>

typedef __bf16 bf16_t;
typedef __bf16 v8bf __attribute__((ext_vector_type(8)));
typedef __bf16 v4bf __attribute__((ext_vector_type(4)));
typedef float  v4f  __attribute__((ext_vector_type(4)));

#define AS1 __attribute__((address_space(1)))
#define AS3 __attribute__((address_space(3)))

// async global->LDS 16B copy; LDS dest = wave-uniform base + lane*16
// (verified safe: rounds 2<->3 manual-vs-async staging gave bit-identical output)
static __device__ __forceinline__ void load_lds16(const bf16_t* g, bf16_t* l) {
    __builtin_amdgcn_global_load_lds((AS1 void*)const_cast<bf16_t*>(g),
                                     (AS3 void*)l, 16, 0, 0);
}

// ---------------------------------------------------------------------------
// Kernel 0: fp32 -> bf16 for h + 4 weights. 8M elems, 8/thread.
// ---------------------------------------------------------------------------
__global__ __launch_bounds__(256) void cvt_fp32_bf16(
    const float* __restrict__ h,  const float* __restrict__ wq,
    const float* __restrict__ wk, const float* __restrict__ wv,
    const float* __restrict__ wo,
    bf16_t* __restrict__ hb,  bf16_t* __restrict__ wqb,
    bf16_t* __restrict__ wkb, bf16_t* __restrict__ wvb,
    bf16_t* __restrict__ wob)
{
    const size_t HM = (size_t)4 << 20;
    const size_t i8 = ((size_t)blockIdx.x * 256 + threadIdx.x) * 8;
    const float* src; bf16_t* dst; size_t off;
    if (i8 < HM) { src = h; dst = hb; off = i8; }
    else {
        const size_t r = (i8 - HM) >> 20;
        off = (i8 - HM) & (((size_t)1 << 20) - 1);
        src = (r == 0) ? wq  : (r == 1) ? wk  : (r == 2) ? wv  : wo;
        dst = (r == 0) ? wqb : (r == 1) ? wkb : (r == 2) ? wvb : wob;
    }
    const float4 a = *(const float4*)(src + off);
    const float4 b = *(const float4*)(src + off + 4);
    v8bf o;
    o[0]=(bf16_t)a.x; o[1]=(bf16_t)a.y; o[2]=(bf16_t)a.z; o[3]=(bf16_t)a.w;
    o[4]=(bf16_t)b.x; o[5]=(bf16_t)b.y; o[6]=(bf16_t)b.z; o[7]=(bf16_t)b.w;
    *(v8bf*)(dst + off) = o;
}

// ---------------------------------------------------------------------------
// Kernel 1: QKV = h @ [wq|wk|wv]^T, fused RoPE on Q,K. All-bf16 inputs,
// global_load_lds staging. Q,K: [32][2048][64]; V TRANSPOSED: [32][64][2048]
// via LDS transpose (coalesced both ends).
// ---------------------------------------------------------------------------
__global__ __launch_bounds__(256) void qkv_gemm_rope(
    const bf16_t* __restrict__ A,   // h bf16 [4096][1024]
    const bf16_t* __restrict__ wq,
    const bf16_t* __restrict__ wk,
    const bf16_t* __restrict__ wv,
    bf16_t* __restrict__ qo, bf16_t* __restrict__ ko, bf16_t* __restrict__ vo)
{
    __shared__ __align__(16) bf16_t smem[8192];  // As|Bs in main loop; Tr in V-epilogue
    bf16_t* As = smem;
    bf16_t* Bs = smem + 4096;

    const int tid = threadIdx.x;
    const int n0  = blockIdx.x * 128;
    const int m0  = blockIdx.y * 128;
    const int sel = n0 >> 10;               // 0=Q 1=K 2=V
    const bf16_t* W = (sel == 0) ? wq : (sel == 1) ? wk : wv;
    const int wr0 = n0 & 1023;

    const int wave = tid >> 6;
    const int lane = tid & 63;
    const int wrow = (wave >> 1) * 64;
    const int wcol = (wave & 1) * 64;
    const int l16  = lane & 15;
    const int quad = lane >> 4;

    v4f acc[4][4];
    #pragma unroll
    for (int i = 0; i < 4; ++i)
        #pragma unroll
        for (int j = 0; j < 4; ++j) acc[i][j] = (v4f)(0.0f);

    for (int kt = 0; kt < 32; ++kt) {
        const int k0 = kt * 32;
        #pragma unroll
        for (int rep = 0; rep < 2; ++rep) {
            const int c   = rep * 256 + tid;     // 16B chunk id
            const int row = c >> 2;
            const int col = (c & 3) * 8;
            load_lds16(A + (size_t)(m0 + row) * 1024 + k0 + col, &As[c * 8]);
            load_lds16(W + (size_t)(wr0 + row) * 1024 + k0 + col, &Bs[c * 8]);
        }
        __syncthreads();

        v8bf af[4], bfb[4];
        #pragma unroll
        for (int i = 0; i < 4; ++i) {
            af[i]  = *(const v8bf*)&As[(wrow + i * 16 + l16) * 32 + quad * 8];
            bfb[i] = *(const v8bf*)&Bs[(wcol + i * 16 + l16) * 32 + quad * 8];
        }
        #pragma unroll
        for (int i = 0; i < 4; ++i)
            #pragma unroll
            for (int j = 0; j < 4; ++j)
                acc[i][j] = __builtin_amdgcn_mfma_f32_16x16x32_bf16(
                    af[i], bfb[j], acc[i][j], 0, 0, 0);
        __syncthreads();
    }

    if (sel < 2) {
        // ---- Q/K epilogue: RoPE + direct store [bh][t][64] ----
        bf16_t* OUT = (sel == 0) ? qo : ko;
        #pragma unroll
        for (int i = 0; i < 4; ++i) {
            #pragma unroll
            for (int j = 0; j < 4; ++j) {
                #pragma unroll
                for (int r = 0; r < 4; ++r) {
                    const int row = wrow + i * 16 + quad * 4 + r;
                    const int col = wcol + j * 16 + l16;
                    const int m = m0 + row;
                    const int n = n0 + col;
                    float v = acc[i][j][r];
                    const float vp = __shfl_xor(v, 1);  // pair col n^1 = lane^1
                    const int t = m & 2047;
                    const int d = n & 63;
                    const int kk = d >> 1;
                    const float freq = exp2f((float)kk * -0.4152410118609203f);
                    const float ang  = (float)t * freq;
                    float sn, cs;
                    sincosf(ang, &sn, &cs);
                    v = ((d & 1) == 0) ? (cs * v - sn * vp) : (sn * vp + cs * v);
                    const int b  = m >> 11;
                    const int hd = (n >> 6) & 15;
                    OUT[(((size_t)(b * 16 + hd) * 2048) + t) * 64 + d] = (bf16_t)v;
                }
            }
        }
    } else {
        // ---- V epilogue: transpose via LDS, store vo[bh][d][t] coalesced ----
        // 4 passes over (pm = m-half, pn = n-half); wave pm*2+pn owns quadrant.
        bf16_t* Tr = smem;                    // [64 n][stride 72] m
        const int b = m0 >> 11;
        #pragma unroll
        for (int pm = 0; pm < 2; ++pm) {
            #pragma unroll
            for (int pn = 0; pn < 2; ++pn) {
                if (wave == pm * 2 + pn) {
                    #pragma unroll
                    for (int i = 0; i < 4; ++i)
                        #pragma unroll
                        for (int j = 0; j < 4; ++j) {
                            v4bf p;
                            #pragma unroll
                            for (int r = 0; r < 4; ++r) p[r] = (bf16_t)acc[i][j][r];
                            // n_local=j*16+l16, m_local=i*16+quad*4 (+r)
                            *(v4bf*)&Tr[(j * 16 + l16) * 72 + i * 16 + quad * 4] = p;
                        }
                }
                __syncthreads();
                const int hd = ((n0 + pn * 64) >> 6) & 15;
                const int t0 = (m0 & 2047) + pm * 64;
                #pragma unroll
                for (int s = 0; s < 2; ++s) {
                    const int ch  = s * 256 + tid;     // 512 chunks of 8
                    const int col = ch >> 3;           // d 0..63
                    const int prt = (ch & 7) * 8;      // t sub-offset
                    const v8bf v = *(const v8bf*)&Tr[col * 72 + prt];
                    *(v8bf*)(vo + (((size_t)(b * 16 + hd) * 64) + col) * 2048 + t0 + prt) = v;
                }
                __syncthreads();
            }
        }
    }
}

// ---------------------------------------------------------------------------
// Kernel 2: causal flash attention, MFMA, paired Q-tiles for perfect balance.
// Block bx handles Q-tiles {31-bx, bx}: (32-bx) + (bx+1) = 33 iters each.
// Software pipeline: next K/V tile prefetched into regs during compute.
// ---------------------------------------------------------------------------
__global__ __launch_bounds__(256) void attn_mfma(
    const bf16_t* __restrict__ qg,
    const bf16_t* __restrict__ kg,
    const bf16_t* __restrict__ vtg,
    bf16_t* __restrict__ og)
{
    __shared__ __align__(16) bf16_t Ks[64 * 72];
    __shared__ __align__(16) bf16_t Vs[64 * 72];
    __shared__ __align__(16) bf16_t Ps[4][16 * 72];

    const int tid  = threadIdx.x;
    const int wave = tid >> 6;
    const int lane = tid & 63;
    const int l16  = lane & 15;
    const int quad = lane >> 4;
    const int bx   = blockIdx.x;   // 0..15
    const int bh   = blockIdx.y;   // 0..31
    const int b = bh >> 4, hh = bh & 15;

    #pragma unroll
    for (int pass = 0; pass < 2; ++pass) {
        const int qt = pass ? bx : (31 - bx);

        // Q A-frags, scale by 1/8 (exact in bf16)
        const bf16_t* qrow = qg + (((size_t)bh * 2048) + (size_t)qt * 64 + wave * 16 + l16) * 64;
        v8bf qf[2];
        qf[0] = *(const v8bf*)(qrow + quad * 8);
        qf[1] = *(const v8bf*)(qrow + 32 + quad * 8);
        #pragma unroll
        for (int e = 0; e < 8; ++e) {
            qf[0][e] = (bf16_t)((float)qf[0][e] * 0.125f);
            qf[1][e] = (bf16_t)((float)qf[1][e] * 0.125f);
        }

        float m_r[4], l_r[4];
        v4f o_acc[4];
        #pragma unroll
        for (int r = 0; r < 4; ++r) { m_r[r] = -1e30f; l_r[r] = 0.0f; }
        #pragma unroll
        for (int dblk = 0; dblk < 4; ++dblk) o_acc[dblk] = (v4f)(0.0f);

        // prefetch kt=0
        v8bf kreg[2], vreg[2];
        #pragma unroll
        for (int rep = 0; rep < 2; ++rep) {
            const int c = rep * 256 + tid;
            const int row = c >> 3, col = (c & 7) * 8;
            kreg[rep] = *(const v8bf*)(kg + (((size_t)bh * 2048) + row) * 64 + col);
            vreg[rep] = *(const v8bf*)(vtg + ((size_t)bh * 64 + row) * 2048 + col);
        }

        for (int kt = 0; kt <= qt; ++kt) {
            __syncthreads();   // prev compute done -> LDS writable
            #pragma unroll
            for (int rep = 0; rep < 2; ++rep) {
                const int c = rep * 256 + tid;
                const int row = c >> 3, col = (c & 7) * 8;
                *(v8bf*)&Ks[row * 72 + col] = kreg[rep];
                *(v8bf*)&Vs[row * 72 + col] = vreg[rep];
            }
            __syncthreads();

            if (kt < qt) {     // prefetch next tile; latency hidden by compute
                #pragma unroll
                for (int rep = 0; rep < 2; ++rep) {
                    const int c = rep * 256 + tid;
                    const int row = c >> 3, col = (c & 7) * 8;
                    kreg[rep] = *(const v8bf*)(kg + (((size_t)bh * 2048) + (size_t)(kt + 1) * 64 + row) * 64 + col);
                    vreg[rep] = *(const v8bf*)(vtg + ((size_t)bh * 64 + row) * 2048 + (size_t)(kt + 1) * 64 + col);
                }
            }

            // ---- S = (Q/8) K^T ----
            v4f s_acc[4];
            #pragma unroll
            for (int kblk = 0; kblk < 4; ++kblk) s_acc[kblk] = (v4f)(0.0f);
            #pragma unroll
            for (int kblk = 0; kblk < 4; ++kblk)
                #pragma unroll
                for (int dblk = 0; dblk < 2; ++dblk) {
                    const v8bf kf = *(const v8bf*)&Ks[(kblk * 16 + l16) * 72 + dblk * 32 + quad * 8];
                    s_acc[kblk] = __builtin_amdgcn_mfma_f32_16x16x32_bf16(
                        qf[dblk], kf, s_acc[kblk], 0, 0, 0);
                }

            if (kt == qt) {    // causal mask on diagonal tile
                #pragma unroll
                for (int kblk = 0; kblk < 4; ++kblk)
                    #pragma unroll
                    for (int r = 0; r < 4; ++r)
                        if (kblk * 16 + l16 > wave * 16 + quad * 4 + r)
                            s_acc[kblk][r] = -1e30f;
            }

            // ---- online softmax (state in regs; 16-lane group reduction) ----
            float alpha[4];
            #pragma unroll
            for (int r = 0; r < 4; ++r) {
                float mx = fmaxf(fmaxf(s_acc[0][r], s_acc[1][r]),
                                 fmaxf(s_acc[2][r], s_acc[3][r]));
                #pragma unroll
                for (int msk = 1; msk < 16; msk <<= 1) mx = fmaxf(mx, __shfl_xor(mx, msk));
                const float m_new = fmaxf(m_r[r], mx);
                float s = 0.0f;
                #pragma unroll
                for (int kblk = 0; kblk < 4; ++kblk) {
                    const float p = __expf(s_acc[kblk][r] - m_new);
                    s_acc[kblk][r] = p;
                    s += p;
                }
                #pragma unroll
                for (int msk = 1; msk < 16; msk <<= 1) s += __shfl_xor(s, msk);
                alpha[r] = __expf(m_r[r] - m_new);
                l_r[r] = l_r[r] * alpha[r] + s;
                m_r[r] = m_new;
            }

            // ---- P: C-layout -> per-wave LDS -> A-layout; O *= alpha ----
            #pragma unroll
            for (int kblk = 0; kblk < 4; ++kblk)
                #pragma unroll
                for (int r = 0; r < 4; ++r)
                    Ps[wave][(quad * 4 + r) * 72 + kblk * 16 + l16] = (bf16_t)s_acc[kblk][r];
            #pragma unroll
            for (int dblk = 0; dblk < 4; ++dblk)
                #pragma unroll
                for (int r = 0; r < 4; ++r)
                    o_acc[dblk][r] *= alpha[r];

            v8bf pf[2];
            pf[0] = *(const v8bf*)&Ps[wave][l16 * 72 + quad * 8];
            pf[1] = *(const v8bf*)&Ps[wave][l16 * 72 + 32 + quad * 8];
            #pragma unroll
            for (int dblk = 0; dblk < 4; ++dblk)
                #pragma unroll
                for (int kk = 0; kk < 2; ++kk) {
                    const v8bf vf = *(const v8bf*)&Vs[(dblk * 16 + l16) * 72 + kk * 32 + quad * 8];
                    o_acc[dblk] = __builtin_amdgcn_mfma_f32_16x16x32_bf16(
                        pf[kk], vf, o_acc[dblk], 0, 0, 0);
                }
        }

        // ---- epilogue: normalize, store og[b][t][h*64+d] ----
        #pragma unroll
        for (int r = 0; r < 4; ++r) {
            const float inv_l = 1.0f / l_r[r];
            const size_t t    = (size_t)qt * 64 + wave * 16 + quad * 4 + r;
            const size_t base = ((size_t)b * 2048 + t) * 1024 + hh * 64;
            #pragma unroll
            for (int dblk = 0; dblk < 4; ++dblk)
                og[base + dblk * 16 + l16] = (bf16_t)(o_acc[dblk][r] * inv_l);
        }
        __syncthreads();   // pass-1 LDS fully consumed before pass-2 overwrites
    }
}

// ---------------------------------------------------------------------------
// Kernel 3: d_out(fp32) = og @ wo^T, all-bf16 staging via global_load_lds.
// ---------------------------------------------------------------------------
__global__ __launch_bounds__(256) void out_gemm(
    const bf16_t* __restrict__ A,   // og [4096][1024] bf16
    const bf16_t* __restrict__ W,   // wob [1024][1024] bf16
    float* __restrict__ C)
{
    __shared__ __align__(16) bf16_t As[128 * 32];
    __shared__ __align__(16) bf16_t Bs[128 * 32];

    const int tid = threadIdx.x;
    const int n0  = blockIdx.x * 128;
    const int m0  = blockIdx.y * 128;

    const int wave = tid >> 6;
    const int lane = tid & 63;
    const int wrow = (wave >> 1) * 64;
    const int wcol = (wave & 1) * 64;
    const int l16  = lane & 15;
    const int quad = lane >> 4;

    v4f acc[4][4];
    #pragma unroll
    for (int i = 0; i < 4; ++i)
        #pragma unroll
        for (int j = 0; j < 4; ++j) acc[i][j] = (v4f)(0.0f);

    for (int kt = 0; kt < 32; ++kt) {
        const int k0 = kt * 32;
        #pragma unroll
        for (int rep = 0; rep < 2; ++rep) {
            const int c   = rep * 256 + tid;
            const int row = c >> 2;
            const int col = (c & 3) * 8;
            load_lds16(A + (size_t)(m0 + row) * 1024 + k0 + col, &As[c * 8]);
            load_lds16(W + (size_t)(n0 + row) * 1024 + k0 + col, &Bs[c * 8]);
        }
        __syncthreads();

        v8bf af[4], bfb[4];
        #pragma unroll
        for (int i = 0; i < 4; ++i) {
            af[i]  = *(const v8bf*)&As[(wrow + i * 16 + l16) * 32 + quad * 8];
            bfb[i] = *(const v8bf*)&Bs[(wcol + i * 16 + l16) * 32 + quad * 8];
        }
        #pragma unroll
        for (int i = 0; i < 4; ++i)
            #pragma unroll
            for (int j = 0; j < 4; ++j)
                acc[i][j] = __builtin_amdgcn_mfma_f32_16x16x32_bf16(
                    af[i], bfb[j], acc[i][j], 0, 0, 0);
        __syncthreads();
    }

    #pragma unroll
    for (int i = 0; i < 4; ++i)
        #pragma unroll
        for (int j = 0; j < 4; ++j)
            #pragma unroll
            for (int r = 0; r < 4; ++r) {
                const int m = m0 + wrow + i * 16 + quad * 4 + r;
                const int n = n0 + wcol + j * 16 + l16;
                C[(size_t)m * 1024 + n] = acc[i][j][r];
            }
}

// ---------------------------------------------------------------------------
extern "C" void kernel_launch(void* const* d_in, const int* in_sizes, int n_in,
                              void* d_out, int out_size, void* d_ws, size_t ws_size,
                              hipStream_t stream) {
    const float* h  = (const float*)d_in[0];
    const float* wq = (const float*)d_in[1];
    const float* wk = (const float*)d_in[2];
    const float* wv = (const float*)d_in[3];
    const float* wo = (const float*)d_in[4];

    const size_t NH = (size_t)4096 * 1024;   // 4M
    const size_t NW = (size_t)1024 * 1024;   // 1M

    bf16_t* hb  = (bf16_t*)d_ws;             // 4M (og aliases after qkv)
    bf16_t* wqb = hb  + NH;
    bf16_t* wkb = wqb + NW;
    bf16_t* wvb = wkb + NW;
    bf16_t* wob = wvb + NW;
    bf16_t* qw  = wob + NW;                  // [32][2048][64]
    bf16_t* kw  = qw + NH;
    bf16_t* vw  = kw + NH;                   // [32][64][2048] (V^T)
    bf16_t* og  = hb;                        // alias: hb dead after qkv
    // total: 20M elems = 40 MB

    cvt_fp32_bf16<<<dim3(4096), dim3(256), 0, stream>>>(
        h, wq, wk, wv, wo, hb, wqb, wkb, wvb, wob);
    qkv_gemm_rope<<<dim3(24, 32), dim3(256), 0, stream>>>(hb, wqb, wkb, wvb, qw, kw, vw);
    attn_mfma<<<dim3(16, 32), dim3(256), 0, stream>>>(qw, kw, vw, og);
    out_gemm<<<dim3(8, 32), dim3(256), 0, stream>>>(og, wob, (float*)d_out);
}

// Round 7
// 213.599 us; speedup vs baseline: 1.9215x; 1.9215x over previous
//
#include <hip/hip_runtime.h>
#include <math.h>

typedef __bf16 bf16_t;
typedef __bf16 v8bf __attribute__((ext_vector_type(8)));
typedef __bf16 v4bf __attribute__((ext_vector_type(4)));
typedef float  v4f  __attribute__((ext_vector_type(4)));

#define AS1 __attribute__((address_space(1)))
#define AS3 __attribute__((address_space(3)))

// async global->LDS 16B copy; LDS dest = wave-uniform base + lane*16
static __device__ __forceinline__ void load_lds16(const bf16_t* g, bf16_t* l) {
    __builtin_amdgcn_global_load_lds((AS1 void*)const_cast<bf16_t*>(g),
                                     (AS3 void*)l, 16, 0, 0);
}

// ---------------------------------------------------------------------------
// Kernel 0: fp32 -> bf16 for h + 4 weights. 8M elems, 8/thread.
// ---------------------------------------------------------------------------
__global__ __launch_bounds__(256) void cvt_fp32_bf16(
    const float* __restrict__ h,  const float* __restrict__ wq,
    const float* __restrict__ wk, const float* __restrict__ wv,
    const float* __restrict__ wo,
    bf16_t* __restrict__ hb,  bf16_t* __restrict__ wqb,
    bf16_t* __restrict__ wkb, bf16_t* __restrict__ wvb,
    bf16_t* __restrict__ wob)
{
    const size_t HM = (size_t)4 << 20;
    const size_t i8 = ((size_t)blockIdx.x * 256 + threadIdx.x) * 8;
    const float* src; bf16_t* dst; size_t off;
    if (i8 < HM) { src = h; dst = hb; off = i8; }
    else {
        const size_t r = (i8 - HM) >> 20;
        off = (i8 - HM) & (((size_t)1 << 20) - 1);
        src = (r == 0) ? wq  : (r == 1) ? wk  : (r == 2) ? wv  : wo;
        dst = (r == 0) ? wqb : (r == 1) ? wkb : (r == 2) ? wvb : wob;
    }
    const float4 a = *(const float4*)(src + off);
    const float4 b = *(const float4*)(src + off + 4);
    v8bf o;
    o[0]=(bf16_t)a.x; o[1]=(bf16_t)a.y; o[2]=(bf16_t)a.z; o[3]=(bf16_t)a.w;
    o[4]=(bf16_t)b.x; o[5]=(bf16_t)b.y; o[6]=(bf16_t)b.z; o[7]=(bf16_t)b.w;
    *(v8bf*)(dst + off) = o;
}

// sin/cos of ang (radians, |ang| < ~2100) via native v_sin/v_cos with explicit
// revolution reduction (HW valid domain); no libcall, no scratch.
static __device__ __forceinline__ void fast_sincos(float ang, float* sn, float* cs) {
    float rv = ang * 0.15915494309189535f;   // to revolutions
    rv -= floorf(rv);                        // [0,1)
    const float a = rv * 6.283185307179586f;
    *sn = __sinf(a);
    *cs = __cosf(a);
}

// ---------------------------------------------------------------------------
// Kernel 1: QKV = h @ [wq|wk|wv]^T, fused RoPE on Q,K. All-bf16 inputs,
// global_load_lds staging. Q,K: [32][2048][64]; V TRANSPOSED: [32][64][2048].
// ALL epilogue global stores are wave-coalesced v8bf (16 B/lane) via per-wave
// LDS staging — no scalar/partial-line global writes.
// ---------------------------------------------------------------------------
__global__ __launch_bounds__(256) void qkv_gemm_rope(
    const bf16_t* __restrict__ A,   // h bf16 [4096][1024]
    const bf16_t* __restrict__ wq,
    const bf16_t* __restrict__ wk,
    const bf16_t* __restrict__ wv,
    bf16_t* __restrict__ qo, bf16_t* __restrict__ ko, bf16_t* __restrict__ vo)
{
    // main loop: As|Bs (8192 elems). epilogue: 4 waves x [64][68] (17408 elems)
    __shared__ __align__(16) bf16_t smem[17408];
    bf16_t* As = smem;
    bf16_t* Bs = smem + 4096;

    const int tid = threadIdx.x;
    const int n0  = blockIdx.x * 128;
    const int m0  = blockIdx.y * 128;
    const int sel = n0 >> 10;               // 0=Q 1=K 2=V
    const bf16_t* W = (sel == 0) ? wq : (sel == 1) ? wk : wv;
    const int wr0 = n0 & 1023;

    const int wave = tid >> 6;
    const int lane = tid & 63;
    const int l16  = lane & 15;
    const int quad = lane >> 4;
    const int wrow = (wave >> 1) * 64;
    const int wcol = (wave & 1) * 64;

    v4f acc[4][4];
    #pragma unroll
    for (int i = 0; i < 4; ++i)
        #pragma unroll
        for (int j = 0; j < 4; ++j) acc[i][j] = (v4f)(0.0f);

    for (int kt = 0; kt < 32; ++kt) {
        const int k0 = kt * 32;
        #pragma unroll
        for (int rep = 0; rep < 2; ++rep) {
            const int c   = rep * 256 + tid;
            const int row = c >> 2;
            const int col = (c & 3) * 8;
            load_lds16(A + (size_t)(m0 + row) * 1024 + k0 + col, &As[c * 8]);
            load_lds16(W + (size_t)(wr0 + row) * 1024 + k0 + col, &Bs[c * 8]);
        }
        __syncthreads();

        v8bf af[4], bfb[4];
        #pragma unroll
        for (int i = 0; i < 4; ++i) {
            af[i]  = *(const v8bf*)&As[(wrow + i * 16 + l16) * 32 + quad * 8];
            bfb[i] = *(const v8bf*)&Bs[(wcol + i * 16 + l16) * 32 + quad * 8];
        }
        #pragma unroll
        for (int i = 0; i < 4; ++i)
            #pragma unroll
            for (int j = 0; j < 4; ++j)
                acc[i][j] = __builtin_amdgcn_mfma_f32_16x16x32_bf16(
                    af[i], bfb[j], acc[i][j], 0, 0, 0);
        __syncthreads();
    }

    // ---- epilogue: per-wave quadrant (m:[wrow,+64), n:[wcol,+64) = 1 head) --
    bf16_t* Ls = smem + wave * 4352;          // [64][stride 68]
    const int bq     = (m0 + wrow) >> 11;
    const int hd     = ((n0 + wcol) >> 6) & 15;
    const int t_base = (m0 + wrow) & 2047;

    if (sel < 2) {
        // Q/K: RoPE in C-layout regs, LDS [m][n], coalesced row stores [bh][t][d]
        bf16_t* OUT = (sel == 0) ? qo : ko;
        #pragma unroll
        for (int i = 0; i < 4; ++i) {
            #pragma unroll
            for (int j = 0; j < 4; ++j) {
                #pragma unroll
                for (int r = 0; r < 4; ++r) {
                    const int mrow = i * 16 + quad * 4 + r;   // local t
                    const int dcol = j * 16 + l16;            // local d (0..63)
                    float v = acc[i][j][r];
                    const float vp = __shfl_xor(v, 1);        // pair d^1 = lane^1
                    const int t  = t_base + mrow;
                    const int kk = dcol >> 1;
                    const float freq = exp2f((float)kk * -0.4152410118609203f);
                    float sn, cs;
                    fast_sincos((float)t * freq, &sn, &cs);
                    v = ((dcol & 1) == 0) ? (cs * v - sn * vp) : (sn * vp + cs * v);
                    Ls[mrow * 68 + dcol] = (bf16_t)v;
                }
            }
        }
        // same-wave LDS RAW: DS pipe is in-order per wave; no barrier needed
        #pragma unroll
        for (int s = 0; s < 8; ++s) {
            const int row = s * 8 + (lane >> 3);
            const int off = (lane & 7) * 8;
            const v8bf vv = *(const v8bf*)&Ls[row * 68 + off];
            *(v8bf*)(OUT + (((size_t)(bq * 16 + hd) * 2048) + t_base + row) * 64 + off) = vv;
        }
    } else {
        // V: transpose via LDS [n][m], coalesced row stores [bh][d][t]
        #pragma unroll
        for (int i = 0; i < 4; ++i)
            #pragma unroll
            for (int j = 0; j < 4; ++j) {
                v4bf p;
                #pragma unroll
                for (int r = 0; r < 4; ++r) p[r] = (bf16_t)acc[i][j][r];
                // C-layout tuple = 4 consecutive m at fixed n -> contiguous in [n][m]
                *(v4bf*)&Ls[(j * 16 + l16) * 68 + i * 16 + quad * 4] = p;
            }
        #pragma unroll
        for (int s = 0; s < 8; ++s) {
            const int drow = s * 8 + (lane >> 3);  // local d
            const int off  = (lane & 7) * 8;       // local t sub-offset
            const v8bf vv = *(const v8bf*)&Ls[drow * 68 + off];
            *(v8bf*)(vo + (((size_t)(bq * 16 + hd) * 64) + drow) * 2048 + t_base + off) = vv;
        }
    }
}

// ---------------------------------------------------------------------------
// Kernel 2: causal flash attention, MFMA, paired Q-tiles (perfect balance) +
// register prefetch of next K/V tile. (unchanged from round 6)
// ---------------------------------------------------------------------------
__global__ __launch_bounds__(256) void attn_mfma(
    const bf16_t* __restrict__ qg,
    const bf16_t* __restrict__ kg,
    const bf16_t* __restrict__ vtg,
    bf16_t* __restrict__ og)
{
    __shared__ __align__(16) bf16_t Ks[64 * 72];
    __shared__ __align__(16) bf16_t Vs[64 * 72];
    __shared__ __align__(16) bf16_t Ps[4][16 * 72];

    const int tid  = threadIdx.x;
    const int wave = tid >> 6;
    const int lane = tid & 63;
    const int l16  = lane & 15;
    const int quad = lane >> 4;
    const int bx   = blockIdx.x;   // 0..15
    const int bh   = blockIdx.y;   // 0..31
    const int b = bh >> 4, hh = bh & 15;

    #pragma unroll
    for (int pass = 0; pass < 2; ++pass) {
        const int qt = pass ? bx : (31 - bx);

        const bf16_t* qrow = qg + (((size_t)bh * 2048) + (size_t)qt * 64 + wave * 16 + l16) * 64;
        v8bf qf[2];
        qf[0] = *(const v8bf*)(qrow + quad * 8);
        qf[1] = *(const v8bf*)(qrow + 32 + quad * 8);
        #pragma unroll
        for (int e = 0; e < 8; ++e) {
            qf[0][e] = (bf16_t)((float)qf[0][e] * 0.125f);
            qf[1][e] = (bf16_t)((float)qf[1][e] * 0.125f);
        }

        float m_r[4], l_r[4];
        v4f o_acc[4];
        #pragma unroll
        for (int r = 0; r < 4; ++r) { m_r[r] = -1e30f; l_r[r] = 0.0f; }
        #pragma unroll
        for (int dblk = 0; dblk < 4; ++dblk) o_acc[dblk] = (v4f)(0.0f);

        v8bf kreg[2], vreg[2];
        #pragma unroll
        for (int rep = 0; rep < 2; ++rep) {
            const int c = rep * 256 + tid;
            const int row = c >> 3, col = (c & 7) * 8;
            kreg[rep] = *(const v8bf*)(kg + (((size_t)bh * 2048) + row) * 64 + col);
            vreg[rep] = *(const v8bf*)(vtg + ((size_t)bh * 64 + row) * 2048 + col);
        }

        for (int kt = 0; kt <= qt; ++kt) {
            __syncthreads();
            #pragma unroll
            for (int rep = 0; rep < 2; ++rep) {
                const int c = rep * 256 + tid;
                const int row = c >> 3, col = (c & 7) * 8;
                *(v8bf*)&Ks[row * 72 + col] = kreg[rep];
                *(v8bf*)&Vs[row * 72 + col] = vreg[rep];
            }
            __syncthreads();

            if (kt < qt) {
                #pragma unroll
                for (int rep = 0; rep < 2; ++rep) {
                    const int c = rep * 256 + tid;
                    const int row = c >> 3, col = (c & 7) * 8;
                    kreg[rep] = *(const v8bf*)(kg + (((size_t)bh * 2048) + (size_t)(kt + 1) * 64 + row) * 64 + col);
                    vreg[rep] = *(const v8bf*)(vtg + ((size_t)bh * 64 + row) * 2048 + (size_t)(kt + 1) * 64 + col);
                }
            }

            v4f s_acc[4];
            #pragma unroll
            for (int kblk = 0; kblk < 4; ++kblk) s_acc[kblk] = (v4f)(0.0f);
            #pragma unroll
            for (int kblk = 0; kblk < 4; ++kblk)
                #pragma unroll
                for (int dblk = 0; dblk < 2; ++dblk) {
                    const v8bf kf = *(const v8bf*)&Ks[(kblk * 16 + l16) * 72 + dblk * 32 + quad * 8];
                    s_acc[kblk] = __builtin_amdgcn_mfma_f32_16x16x32_bf16(
                        qf[dblk], kf, s_acc[kblk], 0, 0, 0);
                }

            if (kt == qt) {
                #pragma unroll
                for (int kblk = 0; kblk < 4; ++kblk)
                    #pragma unroll
                    for (int r = 0; r < 4; ++r)
                        if (kblk * 16 + l16 > wave * 16 + quad * 4 + r)
                            s_acc[kblk][r] = -1e30f;
            }

            float alpha[4];
            #pragma unroll
            for (int r = 0; r < 4; ++r) {
                float mx = fmaxf(fmaxf(s_acc[0][r], s_acc[1][r]),
                                 fmaxf(s_acc[2][r], s_acc[3][r]));
                #pragma unroll
                for (int msk = 1; msk < 16; msk <<= 1) mx = fmaxf(mx, __shfl_xor(mx, msk));
                const float m_new = fmaxf(m_r[r], mx);
                float s = 0.0f;
                #pragma unroll
                for (int kblk = 0; kblk < 4; ++kblk) {
                    const float p = __expf(s_acc[kblk][r] - m_new);
                    s_acc[kblk][r] = p;
                    s += p;
                }
                #pragma unroll
                for (int msk = 1; msk < 16; msk <<= 1) s += __shfl_xor(s, msk);
                alpha[r] = __expf(m_r[r] - m_new);
                l_r[r] = l_r[r] * alpha[r] + s;
                m_r[r] = m_new;
            }

            #pragma unroll
            for (int kblk = 0; kblk < 4; ++kblk)
                #pragma unroll
                for (int r = 0; r < 4; ++r)
                    Ps[wave][(quad * 4 + r) * 72 + kblk * 16 + l16] = (bf16_t)s_acc[kblk][r];
            #pragma unroll
            for (int dblk = 0; dblk < 4; ++dblk)
                #pragma unroll
                for (int r = 0; r < 4; ++r)
                    o_acc[dblk][r] *= alpha[r];

            v8bf pf[2];
            pf[0] = *(const v8bf*)&Ps[wave][l16 * 72 + quad * 8];
            pf[1] = *(const v8bf*)&Ps[wave][l16 * 72 + 32 + quad * 8];
            #pragma unroll
            for (int dblk = 0; dblk < 4; ++dblk)
                #pragma unroll
                for (int kk = 0; kk < 2; ++kk) {
                    const v8bf vf = *(const v8bf*)&Vs[(dblk * 16 + l16) * 72 + kk * 32 + quad * 8];
                    o_acc[dblk] = __builtin_amdgcn_mfma_f32_16x16x32_bf16(
                        pf[kk], vf, o_acc[dblk], 0, 0, 0);
                }
        }

        #pragma unroll
        for (int r = 0; r < 4; ++r) {
            const float inv_l = 1.0f / l_r[r];
            const size_t t    = (size_t)qt * 64 + wave * 16 + quad * 4 + r;
            const size_t base = ((size_t)b * 2048 + t) * 1024 + hh * 64;
            #pragma unroll
            for (int dblk = 0; dblk < 4; ++dblk)
                og[base + dblk * 16 + l16] = (bf16_t)(o_acc[dblk][r] * inv_l);
        }
        __syncthreads();
    }
}

// ---------------------------------------------------------------------------
// Kernel 3: d_out(fp32) = og @ wo^T. Coalesced float2 stores via LDS.
// ---------------------------------------------------------------------------
__global__ __launch_bounds__(256) void out_gemm(
    const bf16_t* __restrict__ A,   // og [4096][1024] bf16
    const bf16_t* __restrict__ W,   // wob [1024][1024] bf16
    float* __restrict__ C)
{
    // main loop: 8192 bf16; epilogue: 4 waves x [32][66] f32 = 8448 f32
    __shared__ __align__(16) float smemf[8448];
    bf16_t* As = (bf16_t*)smemf;
    bf16_t* Bs = As + 4096;

    const int tid = threadIdx.x;
    const int n0  = blockIdx.x * 128;
    const int m0  = blockIdx.y * 128;

    const int wave = tid >> 6;
    const int lane = tid & 63;
    const int l16  = lane & 15;
    const int quad = lane >> 4;
    const int wrow = (wave >> 1) * 64;
    const int wcol = (wave & 1) * 64;

    v4f acc[4][4];
    #pragma unroll
    for (int i = 0; i < 4; ++i)
        #pragma unroll
        for (int j = 0; j < 4; ++j) acc[i][j] = (v4f)(0.0f);

    for (int kt = 0; kt < 32; ++kt) {
        const int k0 = kt * 32;
        #pragma unroll
        for (int rep = 0; rep < 2; ++rep) {
            const int c   = rep * 256 + tid;
            const int row = c >> 2;
            const int col = (c & 3) * 8;
            load_lds16(A + (size_t)(m0 + row) * 1024 + k0 + col, &As[c * 8]);
            load_lds16(W + (size_t)(n0 + row) * 1024 + k0 + col, &Bs[c * 8]);
        }
        __syncthreads();

        v8bf af[4], bfb[4];
        #pragma unroll
        for (int i = 0; i < 4; ++i) {
            af[i]  = *(const v8bf*)&As[(wrow + i * 16 + l16) * 32 + quad * 8];
            bfb[i] = *(const v8bf*)&Bs[(wcol + i * 16 + l16) * 32 + quad * 8];
        }
        #pragma unroll
        for (int i = 0; i < 4; ++i)
            #pragma unroll
            for (int j = 0; j < 4; ++j)
                acc[i][j] = __builtin_amdgcn_mfma_f32_16x16x32_bf16(
                    af[i], bfb[j], acc[i][j], 0, 0, 0);
        __syncthreads();
    }

    // ---- epilogue: per-wave [32][66] f32 staging, float2 coalesced stores ----
    float* Lw = smemf + wave * 2112;
    #pragma unroll
    for (int half = 0; half < 2; ++half) {
        #pragma unroll
        for (int ii = 0; ii < 2; ++ii) {
            const int i = half * 2 + ii;
            #pragma unroll
            for (int j = 0; j < 4; ++j)
                #pragma unroll
                for (int r = 0; r < 4; ++r)
                    Lw[(ii * 16 + quad * 4 + r) * 66 + j * 16 + l16] = acc[i][j][r];
        }
        __syncthreads();
        #pragma unroll
        for (int s = 0; s < 16; ++s) {
            const int row = s * 2 + (lane >> 5);      // 0..31
            const int off = (lane & 31) * 2;          // 0..62 even
            const float2 vv = *(const float2*)&Lw[row * 66 + off];
            *(float2*)(C + (size_t)(m0 + wrow + half * 32 + row) * 1024 + n0 + wcol + off) = vv;
        }
        __syncthreads();
    }
}

// ---------------------------------------------------------------------------
extern "C" void kernel_launch(void* const* d_in, const int* in_sizes, int n_in,
                              void* d_out, int out_size, void* d_ws, size_t ws_size,
                              hipStream_t stream) {
    const float* h  = (const float*)d_in[0];
    const float* wq = (const float*)d_in[1];
    const float* wk = (const float*)d_in[2];
    const float* wv = (const float*)d_in[3];
    const float* wo = (const float*)d_in[4];

    const size_t NH = (size_t)4096 * 1024;   // 4M
    const size_t NW = (size_t)1024 * 1024;   // 1M

    bf16_t* hb  = (bf16_t*)d_ws;             // 4M (og aliases after qkv)
    bf16_t* wqb = hb  + NH;
    bf16_t* wkb = wqb + NW;
    bf16_t* wvb = wkb + NW;
    bf16_t* wob = wvb + NW;
    bf16_t* qw  = wob + NW;                  // [32][2048][64]
    bf16_t* kw  = qw + NH;
    bf16_t* vw  = kw + NH;                   // [32][64][2048] (V^T)
    bf16_t* og  = hb;                        // alias: hb dead after qkv
    // total: 20M elems = 40 MB

    cvt_fp32_bf16<<<dim3(4096), dim3(256), 0, stream>>>(
        h, wq, wk, wv, wo, hb, wqb, wkb, wvb, wob);
    qkv_gemm_rope<<<dim3(24, 32), dim3(256), 0, stream>>>(hb, wqb, wkb, wvb, qw, kw, vw);
    attn_mfma<<<dim3(16, 32), dim3(256), 0, stream>>>(qw, kw, vw, og);
    out_gemm<<<dim3(8, 32), dim3(256), 0, stream>>>(og, wob, (float*)d_out);
}